// Round 1
// baseline (4943.106 us; speedup 1.0000x reference)
//
#include <hip/hip_runtime.h>
#include <cstdint>

#define B_ 8
#define S_ 128
#define T_ 24
#define E_ 512
#define H_ 512
#define H3_ 1536
#define L_ 256
#define D_ 2048

__device__ __forceinline__ float fsig(float x) { return 1.0f / (1.0f + __expf(-x)); }
__device__ __forceinline__ float ftanh(float x) { return 1.0f - 2.0f / (1.0f + __expf(2.0f * x)); }
__device__ __forceinline__ float dot4(float4 a, float4 b) {
    return a.x * b.x + a.y * b.y + a.z * b.z + a.w * b.w;
}

// ---------------------------------------------------------------------------
// Init: build gather index arrays, zero sync counters.
// ---------------------------------------------------------------------------
__global__ void k_init(const int* __restrict__ pre, const int* __restrict__ post,
                       const int* __restrict__ trg,
                       int* __restrict__ idxPre, int* __restrict__ idxPost,
                       int* __restrict__ idxTok, int* __restrict__ cnt) {
    int tid = blockIdx.x * 256 + threadIdx.x;  // grid 4 x 256 = 1024
    if (tid < 1024) {
        int s = tid >> 3, b = tid & 7;
        idxPre[tid]  = pre[b * S_ + s];
        idxPost[tid] = post[b * S_ + s];
    }
    if (tid < T_ * B_) {
        int t = tid >> 3, b = tid & 7;
        idxTok[tid] = (t == 0) ? pre[b * S_ + (S_ - 1)] : trg[b * T_ + (t - 1)];
    }
    if (tid < 8) cnt[tid] = 0;
}

// ---------------------------------------------------------------------------
// Tiled f32 GEMM: C[m][n] = sum_k A[m][k]*B[n][k] + bias[n]
// A row m is (Aidx ? emb-style gather : direct). M,N multiples of 64, K of 16.
// ---------------------------------------------------------------------------
__global__ __launch_bounds__(256) void k_gemm(
    const float* __restrict__ A, const int* __restrict__ Aidx, int lda,
    const float* __restrict__ Bm, int ldb,
    const float* __restrict__ bias, float* __restrict__ C,
    int N, int K) {
    __shared__ float As[16][68];
    __shared__ float Bs[16][68];
    const int m0 = blockIdx.x * 64, n0 = blockIdx.y * 64;
    const int tid = threadIdx.x;
    const int tm = tid >> 2;
    const int tk = (tid & 3) << 2;
    const int tx = tid & 15, ty = tid >> 4;
    const int am = m0 + tm;
    const float* Arow = A + (size_t)(Aidx ? Aidx[am] : am) * lda;
    const float* Brow = Bm + (size_t)(n0 + tm) * ldb;
    float acc[4][4] = {};
    for (int k0 = 0; k0 < K; k0 += 16) {
        float4 av = *(const float4*)(Arow + k0 + tk);
        float4 bv = *(const float4*)(Brow + k0 + tk);
        __syncthreads();
        As[tk][tm] = av.x; As[tk + 1][tm] = av.y; As[tk + 2][tm] = av.z; As[tk + 3][tm] = av.w;
        Bs[tk][tm] = bv.x; Bs[tk + 1][tm] = bv.y; Bs[tk + 2][tm] = bv.z; Bs[tk + 3][tm] = bv.w;
        __syncthreads();
#pragma unroll
        for (int k = 0; k < 16; ++k) {
            float4 a4 = *(const float4*)(&As[k][ty << 2]);
            float4 b4 = *(const float4*)(&Bs[k][tx << 2]);
            float ar[4] = {a4.x, a4.y, a4.z, a4.w};
            float br[4] = {b4.x, b4.y, b4.z, b4.w};
#pragma unroll
            for (int i = 0; i < 4; ++i)
#pragma unroll
                for (int j = 0; j < 4; ++j) acc[i][j] += ar[i] * br[j];
        }
    }
    float4 bb = bias ? *(const float4*)(bias + n0 + (tx << 2)) : make_float4(0.f, 0.f, 0.f, 0.f);
#pragma unroll
    for (int i = 0; i < 4; ++i) {
        int m = m0 + (ty << 2) + i;
        float4 o;
        o.x = acc[i][0] + bb.x; o.y = acc[i][1] + bb.y;
        o.z = acc[i][2] + bb.z; o.w = acc[i][3] + bb.w;
        *(float4*)(C + (size_t)m * N + n0 + (tx << 2)) = o;
    }
}

// ---------------------------------------------------------------------------
// w_eff[k] = sum_j fc_out_W[j] * fc_hid_W[j][k];  b_eff = v.fc_hid_b + fc_out_b
// ---------------------------------------------------------------------------
__global__ void k_weff(const float* __restrict__ fcW, const float* __restrict__ fcB,
                       const float* __restrict__ voW, const float* __restrict__ voB,
                       float* __restrict__ wEff, float* __restrict__ bEff) {
    __shared__ float red[256];
    if (blockIdx.x < 8) {
        int k = blockIdx.x * 256 + threadIdx.x;
        float acc = 0.f;
        for (int j = 0; j < D_; ++j) acc += voW[j] * fcW[(size_t)j * D_ + k];
        wEff[k] = acc;
    } else {
        float p = 0.f;
        for (int j = threadIdx.x; j < D_; j += 256) p += voW[j] * fcB[j];
        red[threadIdx.x] = p;
        __syncthreads();
        for (int s = 128; s > 0; s >>= 1) {
            if (threadIdx.x < s) red[threadIdx.x] += red[threadIdx.x + s];
            __syncthreads();
        }
        if (threadIdx.x == 0) bEff[0] = red[0] + voB[0];
    }
}

// ---------------------------------------------------------------------------
// Encoder scan: 64 wgs (32 per GRU), each owns 16 h-columns (48 Whh rows).
// Flag-synced step barrier within each GRU's 32 wgs.
// ---------------------------------------------------------------------------
__global__ __launch_bounds__(384) void k_encoder(
    const float* __restrict__ giPre, const float* __restrict__ giPost,
    const float* __restrict__ WhhPre, const float* __restrict__ WhhPost,
    const float* __restrict__ bhhPre, const float* __restrict__ bhhPost,
    float* __restrict__ encOut, int* __restrict__ cnt) {
    const int g = blockIdx.x >> 5;        // 0 = pre, 1 = post
    const int cchunk = blockIdx.x & 31;
    const int j0 = cchunk << 4;
    const float* gi = g ? giPost : giPre;
    const float* Whh = g ? WhhPost : WhhPre;
    const float* bhh = g ? bhhPost : bhhPre;
    int* myCnt = cnt + g;

    __shared__ float hS[8 * 516];
    __shared__ float ghS[48 * 8];
    __shared__ float bhhS[48];

    const int tid = threadIdx.x;
    const int b8 = tid & 7;
    const int i48 = tid >> 3;
    const int grow = (i48 >> 4) * 512 + j0 + (i48 & 15);
    if (tid < 48) bhhS[tid] = bhh[(tid >> 4) * 512 + j0 + (tid & 15)];
    const float4* wr4 = (const float4*)(Whh + (size_t)grow * 512);

    for (int t = 0; t < S_; ++t) {
        if (t == 0) {
            for (int i = tid; i < 8 * 516; i += 384) hS[i] = 0.f;
        } else {
            for (int i = tid; i < 4096; i += 384) {
                int b = i >> 9, k = i & 511;
                hS[b * 516 + k] = encOut[(((size_t)(b << 8) + (g << 7) + t - 1) << 9) + k];
            }
        }
        __syncthreads();
        // gh = h @ Whh_chunk^T + bhh
        {
            const float4* h4 = (const float4*)(hS + b8 * 516);
            float acc = 0.f;
#pragma unroll 4
            for (int kk = 0; kk < 128; ++kk) acc += dot4(wr4[kk], h4[kk]);
            ghS[i48 * 8 + b8] = acc + bhhS[i48];
        }
        __syncthreads();
        if (tid < 128) {
            int b = tid & 7, jj = tid >> 3, j = j0 + jj;
            size_t gbase = ((size_t)t * 8 + b) * H3_;
            float gir = gi[gbase + j], giz = gi[gbase + 512 + j], gin = gi[gbase + 1024 + j];
            float ghr = ghS[jj * 8 + b], ghz = ghS[(16 + jj) * 8 + b], ghn = ghS[(32 + jj) * 8 + b];
            float r = fsig(gir + ghr), z = fsig(giz + ghz);
            float n = ftanh(gin + r * ghn);
            float h2 = (1.f - z) * n + z * hS[b * 516 + j];
            encOut[(((size_t)(b << 8) + (g << 7) + t) << 9) + j] = h2;
        }
        __syncthreads();
        if (tid == 0) {
            __threadfence();
            atomicAdd(myCnt, 1);
            int target = 32 * (t + 1);
            while (__hip_atomic_load(myCnt, __ATOMIC_ACQUIRE, __HIP_MEMORY_SCOPE_AGENT) < target) {
                __builtin_amdgcn_s_sleep(1);
            }
        }
        __syncthreads();
        __threadfence();
    }
}

// ---------------------------------------------------------------------------
// hidden = tanh([pre_h|post_h] @ fc_enc_W^T + b) -> decoder h0
// ---------------------------------------------------------------------------
__global__ void k_fcenc(const float* __restrict__ encOut, const float* __restrict__ W,
                        const float* __restrict__ bias, float* __restrict__ h) {
    int o = blockIdx.x * 256 + threadIdx.x;  // grid 16 -> 4096
    int b = o >> 9, j = o & 511;
    const float4* w4 = (const float4*)(W + (size_t)j * 1024);
    const float4* pre4 = (const float4*)(encOut + (((size_t)(b << 8) + 127) << 9));
    const float4* post4 = (const float4*)(encOut + (((size_t)(b << 8) + 255) << 9));
    float acc = bias[j];
    for (int k = 0; k < 128; ++k) acc += dot4(w4[k], pre4[k]);
    for (int k = 0; k < 128; ++k) acc += dot4(w4[128 + k], post4[k]);
    h[o] = ftanh(acc);
}

// enc_dot[b*256+l] = enc_out[b,l,:] . w_eff[0:512]
__global__ void k_encdot(const float* __restrict__ encOut, const float* __restrict__ wEff,
                         float* __restrict__ encDot) {
    int wid = threadIdx.x >> 6, lane = threadIdx.x & 63;
    int gw = blockIdx.x * 4 + wid;  // grid 32 -> 128 waves
    for (int o = gw; o < 2048; o += 128) {
        const float* row = encOut + ((size_t)o << 9);
        float s = 0.f;
        for (int k = lane; k < 512; k += 64) s += row[k] * wEff[k];
        for (int off = 32; off; off >>= 1) s += __shfl_down(s, off);
        if (lane == 0) encDot[o] = s;
    }
}

// eDot4[t*8+b] = emb[tok[t,b]] . w_eff[1536:2048]
__global__ void k_edot4(const float* __restrict__ emb, const int* __restrict__ idxTok,
                        const float* __restrict__ wEff, float* __restrict__ eDot4) {
    int o = blockIdx.x;  // grid 192, block 64
    int lane = threadIdx.x;
    const float* row = emb + (size_t)idxTok[o] * E_;
    const float* w = wEff + 1536;
    float s = 0.f;
    for (int k = lane; k < 512; k += 64) s += row[k] * w[k];
    for (int off = 32; off; off >>= 1) s += __shfl_down(s, off);
    if (lane == 0) eDot4[o] = s;
}

// ---------------------------------------------------------------------------
// Decoder scan: 64 wgs, 5 flag-synced phases per step.
// ---------------------------------------------------------------------------
__global__ __launch_bounds__(256) void k_decoder(
    const float* __restrict__ encOut, const float* __restrict__ encProj,
    const float* __restrict__ attnW, const float* __restrict__ attnV,
    const float* __restrict__ WihDec, const float* __restrict__ WhhDec,
    const float* __restrict__ bhhDec, const float* __restrict__ giE,
    const float* __restrict__ wEff, const float* __restrict__ bEff,
    const float* __restrict__ eDot4,
    float* __restrict__ h, float* __restrict__ hp, float* __restrict__ scores,
    float* __restrict__ weighted, float* __restrict__ gi2, float* __restrict__ gh2,
    float* __restrict__ c, int* __restrict__ cnt) {
    const int tid = threadIdx.x;
    const int bx = blockIdx.x;
    __shared__ float red[256];
    __shared__ float aS[256];
    int ep = 0;
    int* myCnt = cnt + 2;

#define GSYNC()                                                                              \
    do {                                                                                     \
        __syncthreads();                                                                     \
        ++ep;                                                                                \
        if (tid == 0) {                                                                      \
            __threadfence();                                                                 \
            atomicAdd(myCnt, 1);                                                             \
            while (__hip_atomic_load(myCnt, __ATOMIC_ACQUIRE, __HIP_MEMORY_SCOPE_AGENT) <    \
                   64 * ep) {                                                                \
                __builtin_amdgcn_s_sleep(1);                                                 \
            }                                                                                \
        }                                                                                    \
        __syncthreads();                                                                     \
        __threadfence();                                                                     \
    } while (0)

    for (int t = 0; t < T_; ++t) {
        // P0: hp = h @ W_hid^T   (4096 outputs)
        if (tid < 64) {
            int o = bx * 64 + tid;
            int b = o >> 9, d = o & 511;
            const float4* h4 = (const float4*)(h + (b << 9));
            const float4* w4 = (const float4*)(attnW + (size_t)d * 1024);
            float acc = 0.f;
            for (int k = 0; k < 128; ++k) acc += dot4(w4[k], h4[k]);
            hp[o] = acc;
        }
        GSYNC();
        // P1: scores[b,l] = v . tanh(enc_proj + hp)
        {
            int wid = tid >> 6, lane = tid & 63;
            int wave = (bx << 2) + wid;
#pragma unroll
            for (int i = 0; i < 8; ++i) {
                int o = wave * 8 + i;
                int b = o >> 8;
                const float* eprow = encProj + ((size_t)o << 9);
                const float* hprow = hp + (b << 9);
                float s = 0.f;
                for (int d = lane; d < 512; d += 64)
                    s += attnV[d] * ftanh(eprow[d] + hprow[d]);
                for (int off = 32; off; off >>= 1) s += __shfl_down(s, off);
                if (lane == 0) scores[o] = s;
            }
        }
        GSYNC();
        // P2: softmax (redundant per b) + weighted + c init
        {
            int b = bx & 7, h0 = (bx >> 3) << 6;
            float sc = scores[(b << 8) + tid];
            red[tid] = sc;
            __syncthreads();
            for (int s = 128; s > 0; s >>= 1) {
                if (tid < s) red[tid] = fmaxf(red[tid], red[tid + s]);
                __syncthreads();
            }
            float mx = red[0];
            __syncthreads();
            float ex = __expf(sc - mx);
            red[tid] = ex;
            __syncthreads();
            for (int s = 128; s > 0; s >>= 1) {
                if (tid < s) red[tid] += red[tid + s];
                __syncthreads();
            }
            float inv = 1.f / red[0];
            aS[tid] = ex * inv;
            __syncthreads();
            if (tid < 64) {
                int hc = h0 + tid;
                float acc = 0.f;
                for (int l = 0; l < 256; ++l)
                    acc += aS[l] * encOut[(((size_t)(b << 8) + l) << 9) + hc];
                weighted[(b << 9) + hc] = acc;
            }
            if (bx < 8 && tid == 0) c[b * T_ + t] = eDot4[t * 8 + b] + bEff[0];
        }
        GSYNC();
        // P3: gates  (gi2 = giE + weighted @ Wih[:,512:]^T ; gh2 = h @ Whh^T + bhh)
        for (int i = tid; i < 384; i += 256) {
            int o = bx * 384 + i;
            if (o < 12288) {
                int b = o / 1536, n = o % 1536;
                const float4* x4 = (const float4*)(weighted + (b << 9));
                const float4* w4 = (const float4*)(WihDec + (size_t)n * 1024 + 512);
                float acc = giE[((size_t)(t << 3) + b) * H3_ + n];
                for (int k = 0; k < 128; ++k) acc += dot4(w4[k], x4[k]);
                gi2[b * H3_ + n] = acc;
            } else {
                int o2 = o - 12288;
                int b = o2 / 1536, n = o2 % 1536;
                const float4* x4 = (const float4*)(h + (b << 9));
                const float4* w4 = (const float4*)(WhhDec + (size_t)n * 512);
                float acc = bhhDec[n];
                for (int k = 0; k < 128; ++k) acc += dot4(w4[k], x4[k]);
                gh2[b * H3_ + n] = acc;
            }
        }
        GSYNC();
        // P4: h2 + c accumulation
        {
            int b = bx & 7, j0 = (bx >> 3) << 6;
            if (tid < 64) {
                int j = j0 + tid;
                float r = fsig(gi2[b * H3_ + j] + gh2[b * H3_ + j]);
                float z = fsig(gi2[b * H3_ + 512 + j] + gh2[b * H3_ + 512 + j]);
                float n = ftanh(gi2[b * H3_ + 1024 + j] + r * gh2[b * H3_ + 1024 + j]);
                float h2 = (1.f - z) * n + z * h[(b << 9) + j];
                h[(b << 9) + j] = h2;
                float partial = h2 * wEff[1024 + j] + weighted[(b << 9) + j] * wEff[512 + j];
                for (int off = 32; off; off >>= 1) partial += __shfl_down(partial, off);
                if (tid == 0) atomicAdd(&c[b * T_ + t], partial);
            }
        }
        GSYNC();
    }
#undef GSYNC
}

// out[b,t,l-part] = enc_dot[b,l] + c[b,t]
__global__ void k_final(const float* __restrict__ encDot, const float* __restrict__ c,
                        float* __restrict__ out) {
    int idx = blockIdx.x * 256 + threadIdx.x;  // grid 192 -> 49152
    const int half = B_ * T_ * S_;
    int w = idx < half ? idx : idx - half;
    int b = w / (T_ * S_);
    int r = w % (T_ * S_);
    int t = r / S_, s = r % S_;
    int l = (idx < half) ? s : (S_ + s);
    out[idx] = encDot[b * L_ + l] + c[b * T_ + t];
}

// ---------------------------------------------------------------------------
extern "C" void kernel_launch(void* const* d_in, const int* in_sizes, int n_in,
                              void* d_out, int out_size, void* d_ws, size_t ws_size,
                              hipStream_t stream) {
    const int* pre = (const int*)d_in[0];
    const int* post = (const int*)d_in[1];
    const int* trg = (const int*)d_in[2];
    const float* emb = (const float*)d_in[3];
    const float* WihPre = (const float*)d_in[4];
    const float* WhhPre = (const float*)d_in[5];
    const float* bihPre = (const float*)d_in[6];
    const float* bhhPre = (const float*)d_in[7];
    const float* WihPost = (const float*)d_in[8];
    const float* WhhPost = (const float*)d_in[9];
    const float* bihPost = (const float*)d_in[10];
    const float* bhhPost = (const float*)d_in[11];
    const float* fcEncW = (const float*)d_in[12];
    const float* fcEncB = (const float*)d_in[13];
    const float* attnW = (const float*)d_in[14];
    const float* attnB = (const float*)d_in[15];
    const float* attnV = (const float*)d_in[16];
    const float* WihDec = (const float*)d_in[17];
    const float* WhhDec = (const float*)d_in[18];
    const float* bihDec = (const float*)d_in[19];
    const float* bhhDec = (const float*)d_in[20];
    const float* fcHidW = (const float*)d_in[21];
    const float* fcHidB = (const float*)d_in[22];
    const float* fcOutW = (const float*)d_in[23];
    const float* fcOutB = (const float*)d_in[24];
    float* outp = (float*)d_out;

    float* base = (float*)d_ws;
    size_t off = 0;
    auto alloc = [&](size_t n) {
        float* p = base + off;
        off += (n + 63) & ~(size_t)63;
        return p;
    };
    float* giPre = alloc(1024 * 1536);
    float* giPost = alloc(1024 * 1536);
    float* giE = alloc(192 * 1536);
    float* encOut = alloc(8 * 256 * 512);
    float* encProj = alloc(8 * 256 * 512);
    float* wEff = alloc(2048);
    float* bEff = alloc(64);
    float* encDot = alloc(2048);
    float* eDot4 = alloc(256);
    float* hBuf = alloc(4096);
    float* hpBuf = alloc(4096);
    float* scoresBuf = alloc(2048);
    float* weightedBuf = alloc(4096);
    float* gi2 = alloc(12288);
    float* gh2 = alloc(12288);
    float* cBuf = alloc(256);
    int* idxPre = (int*)alloc(1024);
    int* idxPost = (int*)alloc(1024);
    int* idxTok = (int*)alloc(256);
    int* cnt = (int*)alloc(64);

    k_init<<<4, 256, 0, stream>>>(pre, post, trg, idxPre, idxPost, idxTok, cnt);
    k_weff<<<9, 256, 0, stream>>>(fcHidW, fcHidB, fcOutW, fcOutB, wEff, bEff);
    // gi GEMMs (embedding rows gathered on the fly)
    k_gemm<<<dim3(16, 24), 256, 0, stream>>>(emb, idxPre, 512, WihPre, 512, bihPre, giPre, 1536, 512);
    k_gemm<<<dim3(16, 24), 256, 0, stream>>>(emb, idxPost, 512, WihPost, 512, bihPost, giPost, 1536, 512);
    k_gemm<<<dim3(3, 24), 256, 0, stream>>>(emb, idxTok, 512, WihDec, 1024, bihDec, giE, 1536, 512);
    // sequential encoder scan (both GRUs in parallel)
    k_encoder<<<64, 384, 0, stream>>>(giPre, giPost, WhhPre, WhhPost, bhhPre, bhhPost, encOut, cnt);
    // enc_proj = enc_out @ W_enc^T + attn_b
    k_gemm<<<dim3(32, 8), 256, 0, stream>>>(encOut, nullptr, 512, attnW + 512, 1024, attnB, encProj, 512, 512);
    k_fcenc<<<16, 256, 0, stream>>>(encOut, fcEncW, fcEncB, hBuf);
    k_encdot<<<32, 256, 0, stream>>>(encOut, wEff, encDot);
    k_edot4<<<192, 64, 0, stream>>>(emb, idxTok, wEff, eDot4);
    // sequential decoder scan
    k_decoder<<<64, 256, 0, stream>>>(encOut, encProj, attnW, attnV, WihDec, WhhDec, bhhDec,
                                      giE, wEff, bEff, eDot4, hBuf, hpBuf, scoresBuf,
                                      weightedBuf, gi2, gh2, cBuf, cnt);
    k_final<<<192, 256, 0, stream>>>(encDot, cBuf, outp);
}

// Round 2
// 2819.840 us; speedup vs baseline: 1.7530x; 1.7530x over previous
//
#include <hip/hip_runtime.h>
#include <cstdint>

#define B_ 8
#define S_ 128
#define T_ 24
#define E_ 512
#define H_ 512
#define H3_ 1536
#define L_ 256
#define D_ 2048

__device__ __forceinline__ float fsig(float x) { return 1.0f / (1.0f + __expf(-x)); }
__device__ __forceinline__ float ftanh(float x) { return 1.0f - 2.0f / (1.0f + __expf(2.0f * x)); }
__device__ __forceinline__ float dot4(float4 a, float4 b) {
    return a.x * b.x + a.y * b.y + a.z * b.z + a.w * b.w;
}

// Coherent (LLC-level) scalar accesses: relaxed agent-scope atomics compile to
// global_load/store_dword sc0 sc1 — bypass non-coherent L1/L2, NO cache-wide
// maintenance ops (the round-1 killer was buffer_wbl2 from __threadfence).
__device__ __forceinline__ float cohLoad(const float* p) {
    return __hip_atomic_load((float*)p, __ATOMIC_RELAXED, __HIP_MEMORY_SCOPE_AGENT);
}
__device__ __forceinline__ void cohStore(float* p, float v) {
    __hip_atomic_store(p, v, __ATOMIC_RELAXED, __HIP_MEMORY_SCOPE_AGENT);
}
__device__ __forceinline__ void cohAdd(float* p, float v) {
    __hip_atomic_fetch_add(p, v, __ATOMIC_RELAXED, __HIP_MEMORY_SCOPE_AGENT);
}

// Cross-WG barrier: __syncthreads drains each wave's vmem (compiler emits
// s_waitcnt vmcnt(0) before s_barrier), so all write-through stores of the WG
// are at the LLC before tid0 signals. No-return atomic add pipelines at LLC.
__device__ __forceinline__ void sigBarrier(int* flag, int target) {
    __syncthreads();
    if (threadIdx.x == 0) {
        asm volatile("s_waitcnt vmcnt(0)" ::: "memory");
        __hip_atomic_fetch_add(flag, 1, __ATOMIC_RELAXED, __HIP_MEMORY_SCOPE_AGENT);
        while (__hip_atomic_load(flag, __ATOMIC_RELAXED, __HIP_MEMORY_SCOPE_AGENT) < target) {
            __builtin_amdgcn_s_sleep(1);
        }
        asm volatile("" ::: "memory");
    }
    __syncthreads();
}

// ---------------------------------------------------------------------------
__global__ void k_init(const int* __restrict__ pre, const int* __restrict__ post,
                       const int* __restrict__ trg,
                       int* __restrict__ idxPre, int* __restrict__ idxPost,
                       int* __restrict__ idxTok, int* __restrict__ cnt,
                       float* __restrict__ wEff) {
    int tid = blockIdx.x * 256 + threadIdx.x;  // grid 8 x 256 = 2048
    if (tid < 1024) {
        int s = tid >> 3, b = tid & 7;
        idxPre[tid]  = pre[b * S_ + s];
        idxPost[tid] = post[b * S_ + s];
    }
    if (tid < T_ * B_) {
        int t = tid >> 3, b = tid & 7;
        idxTok[tid] = (t == 0) ? pre[b * S_ + (S_ - 1)] : trg[b * T_ + (t - 1)];
    }
    if (tid < 8) cnt[tid] = 0;
    wEff[tid] = 0.f;
}

// ---------------------------------------------------------------------------
// Tiled f32 GEMM: C[m][n] = sum_k A[m][k]*B[n][k] + bias[n]
// ---------------------------------------------------------------------------
__global__ __launch_bounds__(256) void k_gemm(
    const float* __restrict__ A, const int* __restrict__ Aidx, int lda,
    const float* __restrict__ Bm, int ldb,
    const float* __restrict__ bias, float* __restrict__ C,
    int N, int K) {
    __shared__ float As[16][68];
    __shared__ float Bs[16][68];
    const int m0 = blockIdx.x * 64, n0 = blockIdx.y * 64;
    const int tid = threadIdx.x;
    const int tm = tid >> 2;
    const int tk = (tid & 3) << 2;
    const int tx = tid & 15, ty = tid >> 4;
    const int am = m0 + tm;
    const float* Arow = A + (size_t)(Aidx ? Aidx[am] : am) * lda;
    const float* Brow = Bm + (size_t)(n0 + tm) * ldb;
    float acc[4][4] = {};
    for (int k0 = 0; k0 < K; k0 += 16) {
        float4 av = *(const float4*)(Arow + k0 + tk);
        float4 bv = *(const float4*)(Brow + k0 + tk);
        __syncthreads();
        As[tk][tm] = av.x; As[tk + 1][tm] = av.y; As[tk + 2][tm] = av.z; As[tk + 3][tm] = av.w;
        Bs[tk][tm] = bv.x; Bs[tk + 1][tm] = bv.y; Bs[tk + 2][tm] = bv.z; Bs[tk + 3][tm] = bv.w;
        __syncthreads();
#pragma unroll
        for (int k = 0; k < 16; ++k) {
            float4 a4 = *(const float4*)(&As[k][ty << 2]);
            float4 b4 = *(const float4*)(&Bs[k][tx << 2]);
            float ar[4] = {a4.x, a4.y, a4.z, a4.w};
            float br[4] = {b4.x, b4.y, b4.z, b4.w};
#pragma unroll
            for (int i = 0; i < 4; ++i)
#pragma unroll
                for (int j = 0; j < 4; ++j) acc[i][j] += ar[i] * br[j];
        }
    }
    float4 bb = bias ? *(const float4*)(bias + n0 + (tx << 2)) : make_float4(0.f, 0.f, 0.f, 0.f);
#pragma unroll
    for (int i = 0; i < 4; ++i) {
        int m = m0 + (ty << 2) + i;
        float4 o;
        o.x = acc[i][0] + bb.x; o.y = acc[i][1] + bb.y;
        o.z = acc[i][2] + bb.z; o.w = acc[i][3] + bb.w;
        *(float4*)(C + (size_t)m * N + n0 + (tx << 2)) = o;
    }
}

// ---------------------------------------------------------------------------
// w_eff = fc_out_W @ fc_hid_W (2048-dot per col), split 128 WGs + f32 atomics.
// b_eff = fc_out_W . fc_hid_b + fc_out_b
// ---------------------------------------------------------------------------
__global__ void k_weff(const float* __restrict__ fcW, const float* __restrict__ fcB,
                       const float* __restrict__ voW, const float* __restrict__ voB,
                       float* __restrict__ wEff, float* __restrict__ bEff) {
    __shared__ float red[256];
    int bx = blockIdx.x;
    if (bx < 128) {
        int cblk = bx & 7, q = bx >> 3;
        int col = cblk * 256 + threadIdx.x;
        int j0 = q * 128;
        float acc = 0.f;
        for (int j = j0; j < j0 + 128; ++j) acc += voW[j] * fcW[(size_t)j * D_ + col];
        atomicAdd(wEff + col, acc);
    } else {
        float p = 0.f;
        for (int j = threadIdx.x; j < D_; j += 256) p += voW[j] * fcB[j];
        red[threadIdx.x] = p;
        __syncthreads();
        for (int s = 128; s > 0; s >>= 1) {
            if (threadIdx.x < s) red[threadIdx.x] += red[threadIdx.x + s];
            __syncthreads();
        }
        if (threadIdx.x == 0) bEff[0] = red[0] + voB[0];
    }
}

// ---------------------------------------------------------------------------
// Encoder scan: 64 wgs (32 per GRU), each owns 16 h-cols (48 Whh rows).
// h broadcast via coherent dword loads; weights stay cached (no fences).
// ---------------------------------------------------------------------------
__global__ __launch_bounds__(384) void k_encoder(
    const float* __restrict__ giPre, const float* __restrict__ giPost,
    const float* __restrict__ WhhPre, const float* __restrict__ WhhPost,
    const float* __restrict__ bhhPre, const float* __restrict__ bhhPost,
    float* __restrict__ encOut, int* __restrict__ cnt) {
    const int g = blockIdx.x >> 5;
    const int cchunk = blockIdx.x & 31;
    const int j0 = cchunk << 4;
    const float* gi = g ? giPost : giPre;
    const float* Whh = g ? WhhPost : WhhPre;
    const float* bhh = g ? bhhPost : bhhPre;
    int* myCnt = cnt + g;

    __shared__ float hS[8 * 516];
    __shared__ float ghS[48 * 8];
    __shared__ float bhhS[48];

    const int tid = threadIdx.x;
    const int b8 = tid & 7;
    const int i48 = tid >> 3;
    const int grow = (i48 >> 4) * 512 + j0 + (i48 & 15);
    if (tid < 48) bhhS[tid] = bhh[(tid >> 4) * 512 + j0 + (tid & 15)];
    const float4* wr4 = (const float4*)(Whh + (size_t)grow * 512);

    for (int t = 0; t < S_; ++t) {
        if (t == 0) {
            for (int i = tid; i < 8 * 516; i += 384) hS[i] = 0.f;
        } else {
            for (int i = tid; i < 4096; i += 384) {
                int b = i >> 9, k = i & 511;
                hS[b * 516 + k] = cohLoad(encOut + ((((size_t)(b << 8) + (g << 7) + t - 1) << 9) + k));
            }
        }
        __syncthreads();
        {
            const float4* h4 = (const float4*)(hS + b8 * 516);
            float acc = 0.f;
#pragma unroll 4
            for (int kk = 0; kk < 128; ++kk) acc += dot4(wr4[kk], h4[kk]);
            ghS[i48 * 8 + b8] = acc + bhhS[i48];
        }
        __syncthreads();
        if (tid < 128) {
            int b = tid & 7, jj = tid >> 3, j = j0 + jj;
            size_t gbase = ((size_t)t * 8 + b) * H3_;
            float gir = gi[gbase + j], giz = gi[gbase + 512 + j], gin = gi[gbase + 1024 + j];
            float ghr = ghS[jj * 8 + b], ghz = ghS[(16 + jj) * 8 + b], ghn = ghS[(32 + jj) * 8 + b];
            float r = fsig(gir + ghr), z = fsig(giz + ghz);
            float n = ftanh(gin + r * ghn);
            float h2 = (1.f - z) * n + z * hS[b * 516 + j];
            cohStore(encOut + ((((size_t)(b << 8) + (g << 7) + t) << 9) + j), h2);
        }
        sigBarrier(myCnt, 32 * (t + 1));
    }
}

// ---------------------------------------------------------------------------
__global__ void k_fcenc(const float* __restrict__ encOut, const float* __restrict__ W,
                        const float* __restrict__ bias, float* __restrict__ h) {
    int o = blockIdx.x * 256 + threadIdx.x;  // grid 16 -> 4096
    int b = o >> 9, j = o & 511;
    const float4* w4 = (const float4*)(W + (size_t)j * 1024);
    const float4* pre4 = (const float4*)(encOut + (((size_t)(b << 8) + 127) << 9));
    const float4* post4 = (const float4*)(encOut + (((size_t)(b << 8) + 255) << 9));
    float acc = bias[j];
    for (int k = 0; k < 128; ++k) acc += dot4(w4[k], pre4[k]);
    for (int k = 0; k < 128; ++k) acc += dot4(w4[128 + k], post4[k]);
    h[o] = ftanh(acc);
}

// enc_dot[b*256+l] = enc_out[b,l,:] . w_eff[0:512]
__global__ void k_encdot(const float* __restrict__ encOut, const float* __restrict__ wEff,
                         float* __restrict__ encDot) {
    int wid = threadIdx.x >> 6, lane = threadIdx.x & 63;
    int gw = blockIdx.x * 4 + wid;  // grid 32 -> 128 waves
    for (int o = gw; o < 2048; o += 128) {
        const float* row = encOut + ((size_t)o << 9);
        float s = 0.f;
        for (int k = lane; k < 512; k += 64) s += row[k] * wEff[k];
        for (int off = 32; off; off >>= 1) s += __shfl_down(s, off);
        if (lane == 0) encDot[o] = s;
    }
}

// eDot4[t*8+b] = emb[tok[t,b]] . w_eff[1536:2048]
__global__ void k_edot4(const float* __restrict__ emb, const int* __restrict__ idxTok,
                        const float* __restrict__ wEff, float* __restrict__ eDot4) {
    int o = blockIdx.x;  // grid 192, block 64
    int lane = threadIdx.x;
    const float* row = emb + (size_t)idxTok[o] * E_;
    const float* w = wEff + 1536;
    float s = 0.f;
    for (int k = lane; k < 512; k += 64) s += row[k] * w[k];
    for (int off = 32; off; off >>= 1) s += __shfl_down(s, off);
    if (lane == 0) eDot4[o] = s;
}

// ---------------------------------------------------------------------------
// Decoder scan: 128 WGs (b = bx>>4, s-slice = bx&15), 4 barriers/step.
// gh2 & weighted slices live in LDS; only hp/scores/h/gi2/c cross WGs.
// ---------------------------------------------------------------------------
__global__ __launch_bounds__(256) void k_decoder(
    const float* __restrict__ encOut, const float* __restrict__ encProj,
    const float* __restrict__ attnW, const float* __restrict__ attnV,
    const float* __restrict__ WihDec, const float* __restrict__ WhhDec,
    const float* __restrict__ bhhDec, const float* __restrict__ giE,
    const float* __restrict__ wEff, const float* __restrict__ bEff,
    const float* __restrict__ eDot4,
    float* __restrict__ h, float* __restrict__ hp, float* __restrict__ scores,
    float* __restrict__ gi2, float* __restrict__ c, int* __restrict__ cnt) {
    const int tid = threadIdx.x;
    const int bx = blockIdx.x;
    const int b = bx >> 4, s = bx & 15;
    int* flag = cnt + 2;
    int ep = 0;

    __shared__ float hB[512];
    __shared__ float hpS[512];
    __shared__ float gh2S[96];
    __shared__ float hpP[32][9];
    __shared__ float red[256];
    __shared__ float aS[256];
    __shared__ float wP[32][9];
    __shared__ float wS[32];

    for (int t = 0; t < T_; ++t) {
        // ---- A: stage h[b]; hp slice; gh2 slice (LDS); gi2 init; c init ----
        hB[tid] = cohLoad(h + (b << 9) + tid);
        hB[tid + 256] = cohLoad(h + (b << 9) + 256 + tid);
        __syncthreads();
        {
            int r = tid >> 3, p = tid & 7;
            const float4* w4 = (const float4*)(attnW + (size_t)(s * 32 + r) * 1024 + p * 64);
            const float4* h4 = (const float4*)(hB + p * 64);
            float acc = 0.f;
#pragma unroll
            for (int k = 0; k < 16; ++k) acc += dot4(w4[k], h4[k]);
            hpP[r][p] = acc;
        }
        if (tid < 96) {
            int g = tid >> 5, j = tid & 31;
            int n = g * 512 + s * 32 + j;
            const float4* w4 = (const float4*)(WhhDec + (size_t)n * 512);
            const float4* h4 = (const float4*)hB;
            float acc = bhhDec[n];
#pragma unroll 4
            for (int k = 0; k < 128; ++k) acc += dot4(w4[k], h4[k]);
            gh2S[tid] = acc;
            cohStore(gi2 + b * H3_ + n, giE[((size_t)(t << 3) + b) * H3_ + n]);
        }
        __syncthreads();
        if (tid < 32) {
            float a = 0.f;
#pragma unroll
            for (int p = 0; p < 8; ++p) a += hpP[tid][p];
            cohStore(hp + (b << 9) + s * 32 + tid, a);
        }
        if (s == 0 && tid == 0) cohStore(c + b * T_ + t, eDot4[t * 8 + b] + bEff[0]);
        sigBarrier(flag, 128 * (++ep));
        // ---- B: stage hp[b]; score rows l = s*16..s*16+16 ----
        hpS[tid] = cohLoad(hp + (b << 9) + tid);
        hpS[tid + 256] = cohLoad(hp + (b << 9) + 256 + tid);
        __syncthreads();
        {
            int wv = tid >> 6, lane = tid & 63;
#pragma unroll
            for (int i = 0; i < 4; ++i) {
                int l = s * 16 + wv * 4 + i;
                const float* eprow = encProj + (((size_t)(b << 8) + l) << 9);
                float sc = 0.f;
                for (int d = lane; d < 512; d += 64)
                    sc += attnV[d] * ftanh(eprow[d] + hpS[d]);
                for (int off = 32; off; off >>= 1) sc += __shfl_down(sc, off);
                if (lane == 0) cohStore(scores + (b << 8) + l, sc);
            }
        }
        sigBarrier(flag, 128 * (++ep));
        // ---- C: softmax; weighted slice; gi2 partial adds ----
        {
            float sc = cohLoad(scores + (b << 8) + tid);
            red[tid] = sc;
            __syncthreads();
            for (int st = 128; st > 0; st >>= 1) {
                if (tid < st) red[tid] = fmaxf(red[tid], red[tid + st]);
                __syncthreads();
            }
            float mx = red[0];
            __syncthreads();
            float ex = __expf(sc - mx);
            red[tid] = ex;
            __syncthreads();
            for (int st = 128; st > 0; st >>= 1) {
                if (tid < st) red[tid] += red[tid + st];
                __syncthreads();
            }
            float inv = 1.f / red[0];
            aS[tid] = ex * inv;
            __syncthreads();
        }
        {
            int j = tid & 31, p = tid >> 5;  // coalesced over j
            int hc = s * 32 + j;
            float acc = 0.f;
            for (int l = p * 32; l < p * 32 + 32; ++l)
                acc += aS[l] * encOut[(((size_t)(b << 8) + l) << 9) + hc];
            wP[j][p] = acc;
        }
        __syncthreads();
        if (tid < 32) {
            float a = 0.f;
#pragma unroll
            for (int p = 0; p < 8; ++p) a += wP[tid][p];
            wS[tid] = a;
        }
        __syncthreads();
        {
            int ks = s * 32;
#pragma unroll
            for (int i = 0; i < 6; ++i) {
                int n = i * 256 + tid;
                const float* w = WihDec + (size_t)n * 1024 + 512 + ks;
                float acc = 0.f;
#pragma unroll
                for (int k = 0; k < 32; ++k) acc += w[k] * wS[k];
                cohAdd(gi2 + b * H3_ + n, acc);
            }
        }
        sigBarrier(flag, 128 * (++ep));
        // ---- D: GRU update + logit-dot partials ----
        if (tid < 32) {
            int j = s * 32 + tid;
            float gr = cohLoad(gi2 + b * H3_ + j);
            float gz = cohLoad(gi2 + b * H3_ + 512 + j);
            float gn = cohLoad(gi2 + b * H3_ + 1024 + j);
            float r = fsig(gr + gh2S[tid]);
            float z = fsig(gz + gh2S[32 + tid]);
            float n = ftanh(gn + r * gh2S[64 + tid]);
            float h2 = (1.f - z) * n + z * hB[j];
            cohStore(h + (b << 9) + j, h2);
            float pc = h2 * wEff[1024 + j] + wS[tid] * wEff[512 + j];
#pragma unroll
            for (int off = 16; off; off >>= 1) pc += __shfl_down(pc, off);
            if (tid == 0) cohAdd(c + b * T_ + t, pc);
        }
        sigBarrier(flag, 128 * (++ep));
    }
}

// out[b,t,l-part] = enc_dot[b,l] + c[b,t]
__global__ void k_final(const float* __restrict__ encDot, const float* __restrict__ c,
                        float* __restrict__ out) {
    int idx = blockIdx.x * 256 + threadIdx.x;  // grid 192 -> 49152
    const int half = B_ * T_ * S_;
    int w = idx < half ? idx : idx - half;
    int b = w / (T_ * S_);
    int r = w % (T_ * S_);
    int t = r / S_, sidx = r % S_;
    int l = (idx < half) ? sidx : (S_ + sidx);
    out[idx] = encDot[b * L_ + l] + c[b * T_ + t];
}

// ---------------------------------------------------------------------------
extern "C" void kernel_launch(void* const* d_in, const int* in_sizes, int n_in,
                              void* d_out, int out_size, void* d_ws, size_t ws_size,
                              hipStream_t stream) {
    const int* pre = (const int*)d_in[0];
    const int* post = (const int*)d_in[1];
    const int* trg = (const int*)d_in[2];
    const float* emb = (const float*)d_in[3];
    const float* WihPre = (const float*)d_in[4];
    const float* WhhPre = (const float*)d_in[5];
    const float* bihPre = (const float*)d_in[6];
    const float* bhhPre = (const float*)d_in[7];
    const float* WihPost = (const float*)d_in[8];
    const float* WhhPost = (const float*)d_in[9];
    const float* bihPost = (const float*)d_in[10];
    const float* bhhPost = (const float*)d_in[11];
    const float* fcEncW = (const float*)d_in[12];
    const float* fcEncB = (const float*)d_in[13];
    const float* attnW = (const float*)d_in[14];
    const float* attnB = (const float*)d_in[15];
    const float* attnV = (const float*)d_in[16];
    const float* WihDec = (const float*)d_in[17];
    const float* WhhDec = (const float*)d_in[18];
    const float* bihDec = (const float*)d_in[19];
    const float* bhhDec = (const float*)d_in[20];
    const float* fcHidW = (const float*)d_in[21];
    const float* fcHidB = (const float*)d_in[22];
    const float* fcOutW = (const float*)d_in[23];
    const float* fcOutB = (const float*)d_in[24];
    float* outp = (float*)d_out;

    float* base = (float*)d_ws;
    size_t off = 0;
    auto alloc = [&](size_t n) {
        float* p = base + off;
        off += (n + 63) & ~(size_t)63;
        return p;
    };
    float* giPre = alloc(1024 * 1536);
    float* giPost = alloc(1024 * 1536);
    float* giE = alloc(192 * 1536);
    float* encOut = alloc(8 * 256 * 512);
    float* encProj = alloc(8 * 256 * 512);
    float* wEff = alloc(2048);
    float* bEff = alloc(64);
    float* encDot = alloc(2048);
    float* eDot4 = alloc(256);
    float* hBuf = alloc(4096);
    float* hpBuf = alloc(4096);
    float* scoresBuf = alloc(2048);
    float* gi2 = alloc(12288);
    float* cBuf = alloc(256);
    int* idxPre = (int*)alloc(1024);
    int* idxPost = (int*)alloc(1024);
    int* idxTok = (int*)alloc(256);
    int* cnt = (int*)alloc(64);

    k_init<<<8, 256, 0, stream>>>(pre, post, trg, idxPre, idxPost, idxTok, cnt, wEff);
    k_weff<<<129, 256, 0, stream>>>(fcHidW, fcHidB, fcOutW, fcOutB, wEff, bEff);
    k_gemm<<<dim3(16, 24), 256, 0, stream>>>(emb, idxPre, 512, WihPre, 512, bihPre, giPre, 1536, 512);
    k_gemm<<<dim3(16, 24), 256, 0, stream>>>(emb, idxPost, 512, WihPost, 512, bihPost, giPost, 1536, 512);
    k_gemm<<<dim3(3, 24), 256, 0, stream>>>(emb, idxTok, 512, WihDec, 1024, bihDec, giE, 1536, 512);
    k_encoder<<<64, 384, 0, stream>>>(giPre, giPost, WhhPre, WhhPost, bhhPre, bhhPost, encOut, cnt);
    k_gemm<<<dim3(32, 8), 256, 0, stream>>>(encOut, nullptr, 512, attnW + 512, 1024, attnB, encProj, 512, 512);
    k_fcenc<<<16, 256, 0, stream>>>(encOut, fcEncW, fcEncB, hBuf);
    k_encdot<<<32, 256, 0, stream>>>(encOut, wEff, encDot);
    k_edot4<<<192, 64, 0, stream>>>(emb, idxTok, wEff, eDot4);
    k_decoder<<<128, 256, 0, stream>>>(encOut, encProj, attnW, attnV, WihDec, WhhDec, bhhDec,
                                       giE, wEff, bEff, eDot4, hBuf, hpBuf, scoresBuf,
                                       gi2, cBuf, cnt);
    k_final<<<192, 256, 0, stream>>>(encDot, cBuf, outp);
}